// Round 1
// baseline (774.847 us; speedup 1.0000x reference)
//
#include <hip/hip_runtime.h>
#include <math.h>

#define B_ 8
#define N_ 2048
#define D_ 512          // Din == Dout == 512
#define NEG_ALPHA 0.1f

// ---------------------------------------------------------------------------
// Kernel 1: hidden = features @ w
// A [B*N x 512] row-major, W [512 x 512] row-major -> H [B*N x 512]
// 64x64 tile, BK=16, 256 threads as 16x16, 4x4 microtile. fp32 VALU.
// ---------------------------------------------------------------------------
#define G1_BM 64
#define G1_BN 64
#define G1_BK 16

__global__ __launch_bounds__(256) void k_hidden(const float* __restrict__ A,
                                                const float* __restrict__ W,
                                                float* __restrict__ H) {
  __shared__ float As[G1_BK][G1_BM + 4];  // +4 keeps float4 reads 16B-aligned
  __shared__ float Bs[G1_BK][G1_BN + 4];
  const int tid = threadIdx.x;
  const int ty = tid >> 4;   // 0..15 -> rows ty*4..+3
  const int tx = tid & 15;   // 0..15 -> cols tx*4..+3
  const int m0 = blockIdx.y * G1_BM;
  const int n0 = blockIdx.x * G1_BN;

  const int la_k = tid & 15;   // k index for A loads
  const int la_m = tid >> 4;   // row, 4 passes stride 16
  const int lb_n = tid & 63;   // col for B loads
  const int lb_k = tid >> 6;   // k, 4 passes stride 4

  float acc[4][4] = {};

  for (int k0 = 0; k0 < D_; k0 += G1_BK) {
#pragma unroll
    for (int p = 0; p < 4; ++p) {
      int m = la_m + p * 16;
      As[la_k][m] = A[(size_t)(m0 + m) * D_ + k0 + la_k];
    }
#pragma unroll
    for (int p = 0; p < 4; ++p) {
      int k = lb_k + p * 4;
      Bs[k][lb_n] = W[(size_t)(k0 + k) * D_ + n0 + lb_n];
    }
    __syncthreads();
#pragma unroll
    for (int k = 0; k < G1_BK; ++k) {
      float4 av = *(const float4*)&As[k][ty * 4];
      float4 bv = *(const float4*)&Bs[k][tx * 4];
      float a[4] = {av.x, av.y, av.z, av.w};
      float b[4] = {bv.x, bv.y, bv.z, bv.w};
#pragma unroll
      for (int i = 0; i < 4; ++i)
#pragma unroll
        for (int j = 0; j < 4; ++j) acc[i][j] = fmaf(a[i], b[j], acc[i][j]);
    }
    __syncthreads();
  }
#pragma unroll
  for (int i = 0; i < 4; ++i) {
    float4 v = make_float4(acc[i][0], acc[i][1], acc[i][2], acc[i][3]);
    *(float4*)&H[(size_t)(m0 + ty * 4 + i) * D_ + n0 + tx * 4] = v;
  }
}

// ---------------------------------------------------------------------------
// Kernel 2: s1[r] = hidden[r,:] . a1 ; s2[r] = hidden[r,:] . a2
// One wave (64 lanes) per row.
// ---------------------------------------------------------------------------
__global__ __launch_bounds__(256) void k_scores(const float* __restrict__ H,
                                                const float* __restrict__ a1,
                                                const float* __restrict__ a2,
                                                float* __restrict__ s1,
                                                float* __restrict__ s2) {
  const int wave = threadIdx.x >> 6;  // 0..3
  const int lane = threadIdx.x & 63;
  const int row = blockIdx.x * 4 + wave;
  const float* h = H + (size_t)row * D_;
  float d1 = 0.f, d2 = 0.f;
#pragma unroll
  for (int q = 0; q < D_ / 64; ++q) {
    int c = lane + q * 64;
    float hv = h[c];
    d1 = fmaf(hv, a1[c], d1);
    d2 = fmaf(hv, a2[c], d2);
  }
#pragma unroll
  for (int off = 32; off > 0; off >>= 1) {
    d1 += __shfl_down(d1, off, 64);
    d2 += __shfl_down(d2, off, 64);
  }
  if (lane == 0) {
    s1[row] = d1;
    s2[row] = d2;
  }
}

// ---------------------------------------------------------------------------
// Kernel 3: out = elu( softmax(mask(leaky(s1_i+s2_j))) @ hidden )
// Single pass: p_ij = graph ? exp(leaky(s1_i+s2_j)) : 0 (no max subtraction
// needed: |e| <~ 30 so exp stays in fp32 range; masked lanes are exactly 0,
// same as reference where exp(-1e9 - max) flushes to 0).
// WG: TM=32 rows x all 512 cols. K-chunks of KC=16. 256 threads.
// Microtile: 4 rows x 16 cols per thread (cols strided by 128 to tame LDS
// bank conflicts to 4-way). Row sums accumulated alongside.
// ---------------------------------------------------------------------------
#define TM 32
#define KC 16

__global__ __launch_bounds__(256) void k_attn(const float* __restrict__ H,
                                              const int* __restrict__ graph,
                                              const float* __restrict__ s1,
                                              const float* __restrict__ s2,
                                              float* __restrict__ out) {
  __shared__ float Hs[KC][D_ + 4];   // 16 x 516 = 33 KB
  __shared__ float Ps[KC][TM];       // P^T chunk, 2 KB
  __shared__ float s2s[N_];          // 8 KB
  __shared__ float sum_part[TM][8];
  __shared__ float row_sum[TM];

  const int tid = threadIdx.x;
  const int b = blockIdx.y;
  const int i0 = blockIdx.x * TM;

  const float* Hb = H + (size_t)b * N_ * D_;
  const int* Gb = graph + (size_t)b * N_ * N_ + (size_t)i0 * N_;

  // stage s2[b][:] once
  for (int c = tid; c < N_; c += 256) s2s[c] = s2[(size_t)b * N_ + c];

  // P-compute mapping: thread -> (row pr, two consecutive j)
  const int pr = tid >> 3;        // 0..31
  const int pj = (tid & 7) * 2;   // 0,2,..,14
  const float s1r = s1[(size_t)b * N_ + i0 + pr];
  float rsum = 0.f;

  // microkernel mapping
  const int ty = tid >> 5;  // 0..7 -> rows ty*4..+3
  const int tx = tid & 31;  // 0..31 -> col groups

  float acc[4][4][4] = {};  // [ri][g][cc]: 64 accumulators

  __syncthreads();  // s2s ready

  for (int j0 = 0; j0 < N_; j0 += KC) {
    // stage Hs chunk: 16 rows x 512 floats = 2048 float4, 8 per thread
#pragma unroll
    for (int p = 0; p < 8; ++p) {
      int idx4 = tid + p * 256;
      int r = idx4 >> 7;
      int c4 = idx4 & 127;
      float4 v = *(const float4*)&Hb[(size_t)(j0 + r) * D_ + c4 * 4];
      *(float4*)&Hs[r][c4 * 4] = v;
    }
    // compute P chunk (transposed) + row-sum partials
    {
      int2 g2 = *(const int2*)&Gb[(size_t)pr * N_ + j0 + pj];
      float e0 = s1r + s2s[j0 + pj];
      float e1 = s1r + s2s[j0 + pj + 1];
      e0 = (e0 > 0.f) ? e0 : NEG_ALPHA * e0;
      e1 = (e1 > 0.f) ? e1 : NEG_ALPHA * e1;
      float p0 = (g2.x != 0) ? __expf(e0) : 0.f;
      float p1 = (g2.y != 0) ? __expf(e1) : 0.f;
      Ps[pj][pr] = p0;
      Ps[pj + 1][pr] = p1;
      rsum += p0 + p1;
    }
    __syncthreads();
    // accumulate O += P^T-chunk @ Hs
#pragma unroll
    for (int j = 0; j < KC; ++j) {
      float4 pv = *(const float4*)&Ps[j][ty * 4];
      float pa[4] = {pv.x, pv.y, pv.z, pv.w};
#pragma unroll
      for (int g = 0; g < 4; ++g) {
        float4 hv = *(const float4*)&Hs[j][(tx + g * 32) * 4];
        float hb4[4] = {hv.x, hv.y, hv.z, hv.w};
#pragma unroll
        for (int ri = 0; ri < 4; ++ri)
#pragma unroll
          for (int cc = 0; cc < 4; ++cc)
            acc[ri][g][cc] = fmaf(pa[ri], hb4[cc], acc[ri][g][cc]);
      }
    }
    __syncthreads();
  }

  // reduce row sums: 8 partials per row
  sum_part[pr][tid & 7] = rsum;
  __syncthreads();
  if (tid < TM) {
    float s = 0.f;
#pragma unroll
    for (int q = 0; q < 8; ++q) s += sum_part[tid][q];
    row_sum[tid] = s;
  }
  __syncthreads();

  // epilogue: normalize + elu + store
#pragma unroll
  for (int ri = 0; ri < 4; ++ri) {
    const int row = i0 + ty * 4 + ri;
    const float inv = 1.f / row_sum[ty * 4 + ri];
#pragma unroll
    for (int g = 0; g < 4; ++g) {
      float vv[4];
#pragma unroll
      for (int cc = 0; cc < 4; ++cc) {
        float x = acc[ri][g][cc] * inv;
        vv[cc] = (x > 0.f) ? x : expm1f(x);
      }
      float4 v = make_float4(vv[0], vv[1], vv[2], vv[3]);
      *(float4*)&out[((size_t)b * N_ + row) * D_ + (size_t)(tx + g * 32) * 4] = v;
    }
  }
}

// ---------------------------------------------------------------------------
extern "C" void kernel_launch(void* const* d_in, const int* in_sizes, int n_in,
                              void* d_out, int out_size, void* d_ws,
                              size_t ws_size, hipStream_t stream) {
  const float* features = (const float*)d_in[0];
  const int* graph = (const int*)d_in[1];
  const float* w = (const float*)d_in[2];
  const float* a1 = (const float*)d_in[3];
  const float* a2 = (const float*)d_in[4];
  float* out = (float*)d_out;

  // workspace: hidden (B*N*D fp32) + s1 + s2  (~33.7 MB)
  float* hidden = (float*)d_ws;
  float* s1 = hidden + (size_t)B_ * N_ * D_;
  float* s2 = s1 + (size_t)B_ * N_;

  dim3 g1(D_ / G1_BN, (B_ * N_) / G1_BM);  // (8, 256)
  hipLaunchKernelGGL(k_hidden, g1, dim3(256), 0, stream, features, w, hidden);

  hipLaunchKernelGGL(k_scores, dim3((B_ * N_) / 4), dim3(256), 0, stream,
                     hidden, a1, a2, s1, s2);

  dim3 g3(N_ / TM, B_);  // (64, 8)
  hipLaunchKernelGGL(k_attn, g3, dim3(256), 0, stream, hidden, graph, s1, s2,
                     out);
}

// Round 2
// 345.106 us; speedup vs baseline: 2.2452x; 2.2452x over previous
//
#include <hip/hip_runtime.h>
#include <math.h>

#define B_ 8
#define N_ 2048
#define D_ 512
#define NROWS (B_ * N_)  // 16384
#define NEG_ALPHA 0.1f

typedef __bf16 bf16;
typedef __bf16 bf16x4 __attribute__((ext_vector_type(4)));
typedef __bf16 bf16x8 __attribute__((ext_vector_type(8)));
typedef float f32x4 __attribute__((ext_vector_type(4)));

// ---------------------------------------------------------------------------
// k_prep: Wt[dout][din] = bf16(W[din][dout])   (A-operand for Ht = Wt * X^T)
// ---------------------------------------------------------------------------
__global__ __launch_bounds__(256) void k_prep(const float* __restrict__ W,
                                              bf16* __restrict__ Wt) {
  const int dout = blockIdx.x;  // 512 blocks
  const int t = threadIdx.x;
#pragma unroll
  for (int p = 0; p < 2; ++p) {
    int din = t + p * 256;
    Wt[dout * D_ + din] = (bf16)W[din * D_ + dout];
  }
}

// ---------------------------------------------------------------------------
// k_wa: wa1 = W @ a1, wa2 = W @ a2  (fp32, exact path for the logits)
// one wave per din-row
// ---------------------------------------------------------------------------
__global__ __launch_bounds__(256) void k_wa(const float* __restrict__ W,
                                            const float* __restrict__ a1,
                                            const float* __restrict__ a2,
                                            float* __restrict__ wa1,
                                            float* __restrict__ wa2) {
  const int wv = threadIdx.x >> 6, lane = threadIdx.x & 63;
  const int row = blockIdx.x * 4 + wv;  // grid 128 -> 512 rows
  const float* wr = W + (size_t)row * D_;
  float d1 = 0.f, d2 = 0.f;
#pragma unroll
  for (int p = 0; p < 8; ++p) {
    int c = lane + p * 64;
    float w = wr[c];
    d1 = fmaf(w, a1[c], d1);
    d2 = fmaf(w, a2[c], d2);
  }
#pragma unroll
  for (int off = 32; off > 0; off >>= 1) {
    d1 += __shfl_down(d1, off, 64);
    d2 += __shfl_down(d2, off, 64);
  }
  if (lane == 0) {
    wa1[row] = d1;
    wa2[row] = d2;
  }
}

// ---------------------------------------------------------------------------
// k_scores_x: s1[r] = X[r,:] . wa1 ; s2[r] = X[r,:] . wa2  (fp32, coalesced)
// one wave per row, 4 waves/block
// ---------------------------------------------------------------------------
__global__ __launch_bounds__(256) void k_scores_x(const float* __restrict__ X,
                                                  const float* __restrict__ wa1,
                                                  const float* __restrict__ wa2,
                                                  float* __restrict__ s1,
                                                  float* __restrict__ s2) {
  const int wv = threadIdx.x >> 6, lane = threadIdx.x & 63;
  const int r = blockIdx.x * 4 + wv;  // grid 4096
  const float* x = X + (size_t)r * D_;
  float d1 = 0.f, d2 = 0.f;
#pragma unroll
  for (int p = 0; p < 2; ++p) {
    int c = lane * 4 + p * 256;
    float4 xv = *(const float4*)&x[c];
    float4 w1 = *(const float4*)&wa1[c];
    float4 w2 = *(const float4*)&wa2[c];
    d1 += xv.x * w1.x + xv.y * w1.y + xv.z * w1.z + xv.w * w1.w;
    d2 += xv.x * w2.x + xv.y * w2.y + xv.z * w2.z + xv.w * w2.w;
  }
#pragma unroll
  for (int off = 32; off > 0; off >>= 1) {
    d1 += __shfl_down(d1, off, 64);
    d2 += __shfl_down(d2, off, 64);
  }
  if (lane == 0) {
    s1[r] = d1;
    s2[r] = d2;
  }
}

// ---------------------------------------------------------------------------
// k_hiddenT: Ht[dout][row] = bf16( sum_din Wt[dout][din] * X[row][din] )
// MFMA GEMM: M=512(dout), N=16384(rows), K=512. BM=BN=128, BK=32.
// 256 thr = 4 waves (2x2), wave does 64x64 = 4x4 tiles of 16x16x32.
// ---------------------------------------------------------------------------
#define LDH 40  // padded LDS leading dim (bf16): 80 B rows -> 16B-aligned, <=2-way banks

__global__ __launch_bounds__(256, 2) void k_hiddenT(const float* __restrict__ X,
                                                    const bf16* __restrict__ Wt,
                                                    bf16* __restrict__ Ht) {
  __shared__ bf16 As[128][LDH];
  __shared__ bf16 Bs[128][LDH];
  const int t = threadIdx.x;
  const int m0 = blockIdx.y * 128;  // dout
  const int n0 = blockIdx.x * 128;  // rows
  const int lane = t & 63, w = t >> 6;
  const int wm = w >> 1, wn = w & 1;
  const int l15 = lane & 15, q = lane >> 4;

  f32x4 acc[4][4];
#pragma unroll
  for (int i = 0; i < 4; ++i)
#pragma unroll
    for (int j = 0; j < 4; ++j) acc[i][j] = (f32x4){0.f, 0.f, 0.f, 0.f};

  for (int k0 = 0; k0 < D_; k0 += 32) {
    // A-tile: Wt rows (bf16, contiguous k)
#pragma unroll
    for (int p = 0; p < 2; ++p) {
      int s = t + p * 256;
      int row = s >> 2, c = s & 3;
      *(bf16x8*)&As[row][c * 8] =
          *(const bf16x8*)&Wt[(size_t)(m0 + row) * D_ + k0 + c * 8];
    }
    // B-tile: X rows fp32 -> bf16
#pragma unroll
    for (int p = 0; p < 4; ++p) {
      int s = t + p * 256;
      int row = s >> 3, c = s & 7;
      float4 v = *(const float4*)&X[(size_t)(n0 + row) * D_ + k0 + c * 4];
      bf16x4 h = {(bf16)v.x, (bf16)v.y, (bf16)v.z, (bf16)v.w};
      *(bf16x4*)&Bs[row][c * 4] = h;
    }
    __syncthreads();
    bf16x8 a[4], bb[4];
#pragma unroll
    for (int i = 0; i < 4; ++i)
      a[i] = *(const bf16x8*)&As[wm * 64 + i * 16 + l15][q * 8];
#pragma unroll
    for (int j = 0; j < 4; ++j)
      bb[j] = *(const bf16x8*)&Bs[wn * 64 + j * 16 + l15][q * 8];
#pragma unroll
    for (int i = 0; i < 4; ++i)
#pragma unroll
      for (int j = 0; j < 4; ++j)
        acc[i][j] =
            __builtin_amdgcn_mfma_f32_16x16x32_bf16(a[i], bb[j], acc[i][j], 0, 0, 0);
    __syncthreads();
  }
  // epilogue: D row = dout = quad*4+reg, col = row-index = lane&15
#pragma unroll
  for (int i = 0; i < 4; ++i)
#pragma unroll
    for (int r = 0; r < 4; ++r) {
      int dout = m0 + wm * 64 + i * 16 + q * 4 + r;
#pragma unroll
      for (int j = 0; j < 4; ++j) {
        int row = n0 + wn * 64 + j * 16 + l15;
        Ht[(size_t)dout * NROWS + row] = (bf16)acc[i][j][r];
      }
    }
}

// ---------------------------------------------------------------------------
// k_attn: out = elu( softmax_row( mask(leaky(s1_i+s2_j)) ) @ H )
// O = P @ H : M=64 rows/block, N=512 (full d), K=2048 (j), BK=32.
// 512 thr = 8 waves; wave w covers d-range [w*64, w*64+64), all 64 rows.
// P chunk generated on the fly (graph read once); unnormalized accumulate
// + fp32 row sums; normalize+elu in epilogue. No max-subtraction needed
// (|e| <~ 30, exp fits fp32; masked -> exactly 0, matching reference).
// ---------------------------------------------------------------------------
#define AT_BM 64
#define AT_BK 32

__global__ __launch_bounds__(512, 2) void k_attn(const bf16* __restrict__ Ht,
                                                 const int* __restrict__ graph,
                                                 const float* __restrict__ s1,
                                                 const float* __restrict__ s2,
                                                 float* __restrict__ out) {
  __shared__ bf16 Hs[D_][LDH];         // 40 KB  [d][j]
  __shared__ bf16 Ps[AT_BM][LDH];      // 5 KB   [i][j]
  __shared__ float s2s[N_];            // 8 KB
  __shared__ float sum_part[AT_BM][8]; // 2 KB
  __shared__ float row_sum[AT_BM];

  const int t = threadIdx.x;
  const int b = blockIdx.y;
  const int i0 = blockIdx.x * AT_BM;
  const int lane = t & 63, w = t >> 6;
  const int l15 = lane & 15, q = lane >> 4;

  const bf16* Htb = Ht + (size_t)b * N_;  // Ht[d][b*2048 + j]
  const int* Gb = graph + ((size_t)b * N_ + i0) * N_;

  for (int c = t; c < N_; c += 512) s2s[c] = s2[b * N_ + c];

  const int pi = t >> 3;         // P row 0..63
  const int pj = (t & 7) * 4;    // P j-offset
  const float s1r = s1[b * N_ + i0 + pi];
  float rsum = 0.f;

  f32x4 acc[4][4];
#pragma unroll
  for (int i = 0; i < 4; ++i)
#pragma unroll
    for (int j = 0; j < 4; ++j) acc[i][j] = (f32x4){0.f, 0.f, 0.f, 0.f};

  __syncthreads();

  for (int j0 = 0; j0 < N_; j0 += AT_BK) {
    // stage Hs: 512 d-rows x 32 j (bf16), 16B chunks
#pragma unroll
    for (int p = 0; p < 4; ++p) {
      int s = t + p * 512;
      int d = s >> 2, c = s & 3;
      *(bf16x8*)&Hs[d][c * 8] =
          *(const bf16x8*)&Htb[(size_t)d * NROWS + j0 + c * 8];
    }
    // P chunk: 64 rows x 32 j, 4 per thread
    {
      int4 g = *(const int4*)&Gb[(size_t)pi * N_ + j0 + pj];
      float e0 = s1r + s2s[j0 + pj + 0];
      float e1 = s1r + s2s[j0 + pj + 1];
      float e2 = s1r + s2s[j0 + pj + 2];
      float e3 = s1r + s2s[j0 + pj + 3];
      e0 = (e0 > 0.f) ? e0 : NEG_ALPHA * e0;
      e1 = (e1 > 0.f) ? e1 : NEG_ALPHA * e1;
      e2 = (e2 > 0.f) ? e2 : NEG_ALPHA * e2;
      e3 = (e3 > 0.f) ? e3 : NEG_ALPHA * e3;
      float p0 = (g.x != 0) ? __expf(e0) : 0.f;
      float p1 = (g.y != 0) ? __expf(e1) : 0.f;
      float p2 = (g.z != 0) ? __expf(e2) : 0.f;
      float p3 = (g.w != 0) ? __expf(e3) : 0.f;
      rsum += (p0 + p1) + (p2 + p3);
      bf16x4 pv = {(bf16)p0, (bf16)p1, (bf16)p2, (bf16)p3};
      *(bf16x4*)&Ps[pi][pj] = pv;
    }
    __syncthreads();
    bf16x8 a[4], h[4];
#pragma unroll
    for (int mi = 0; mi < 4; ++mi)
      a[mi] = *(const bf16x8*)&Ps[mi * 16 + l15][q * 8];
#pragma unroll
    for (int ni = 0; ni < 4; ++ni)
      h[ni] = *(const bf16x8*)&Hs[w * 64 + ni * 16 + l15][q * 8];
#pragma unroll
    for (int mi = 0; mi < 4; ++mi)
#pragma unroll
      for (int ni = 0; ni < 4; ++ni)
        acc[mi][ni] =
            __builtin_amdgcn_mfma_f32_16x16x32_bf16(a[mi], h[ni], acc[mi][ni], 0, 0, 0);
    __syncthreads();
  }

  // row sums
  sum_part[pi][t & 7] = rsum;
  __syncthreads();
  if (t < AT_BM) {
    float s = 0.f;
#pragma unroll
    for (int k = 0; k < 8; ++k) s += sum_part[t][k];
    row_sum[t] = s;
  }
  __syncthreads();

  // epilogue: normalize + elu + store
#pragma unroll
  for (int mi = 0; mi < 4; ++mi)
#pragma unroll
    for (int r = 0; r < 4; ++r) {
      int m = mi * 16 + q * 4 + r;
      float inv = 1.f / row_sum[m];
      size_t rowbase = ((size_t)b * N_ + i0 + m) * D_;
#pragma unroll
      for (int ni = 0; ni < 4; ++ni) {
        int d = w * 64 + ni * 16 + l15;
        float x = acc[mi][ni][r] * inv;
        out[rowbase + d] = (x > 0.f) ? x : expm1f(x);
      }
    }
}

// ---------------------------------------------------------------------------
extern "C" void kernel_launch(void* const* d_in, const int* in_sizes, int n_in,
                              void* d_out, int out_size, void* d_ws,
                              size_t ws_size, hipStream_t stream) {
  const float* X = (const float*)d_in[0];
  const int* graph = (const int*)d_in[1];
  const float* W = (const float*)d_in[2];
  const float* a1 = (const float*)d_in[3];
  const float* a2 = (const float*)d_in[4];
  float* out = (float*)d_out;

  // workspace layout (bytes):
  char* ws = (char*)d_ws;
  bf16* Wt = (bf16*)ws;                               // 512*512*2   = 512 KB
  bf16* Ht = (bf16*)(ws + (1 << 19));                 // 16384*512*2 = 16 MB
  float* s1 = (float*)(ws + (1 << 19) + (16 << 20));  // 64 KB
  float* s2 = s1 + NROWS;
  float* wa1 = s2 + NROWS;
  float* wa2 = wa1 + D_;

  hipLaunchKernelGGL(k_prep, dim3(512), dim3(256), 0, stream, W, Wt);
  hipLaunchKernelGGL(k_wa, dim3(128), dim3(256), 0, stream, W, a1, a2, wa1, wa2);
  hipLaunchKernelGGL(k_scores_x, dim3(NROWS / 4), dim3(256), 0, stream, X, wa1,
                     wa2, s1, s2);
  hipLaunchKernelGGL(k_hiddenT, dim3(NROWS / 128, D_ / 128), dim3(256), 0,
                     stream, X, Wt, Ht);
  hipLaunchKernelGGL(k_attn, dim3(N_ / AT_BM, B_), dim3(512), 0, stream, Ht,
                     graph, s1, s2, out);
}

// Round 3
// 305.131 us; speedup vs baseline: 2.5394x; 1.1310x over previous
//
#include <hip/hip_runtime.h>
#include <math.h>

#define B_ 8
#define N_ 2048
#define D_ 512
#define NROWS (B_ * N_)  // 16384
#define NEG_ALPHA 0.1f

typedef __bf16 bf16;
typedef __bf16 bf16x4 __attribute__((ext_vector_type(4)));
typedef __bf16 bf16x8 __attribute__((ext_vector_type(8)));
typedef float f32x4 __attribute__((ext_vector_type(4)));
typedef float f32x16 __attribute__((ext_vector_type(16)));

// ---------------------------------------------------------------------------
// k_prep: Wt[dout][din] = bf16(W[din][dout])
// ---------------------------------------------------------------------------
__global__ __launch_bounds__(256) void k_prep(const float* __restrict__ W,
                                              bf16* __restrict__ Wt) {
  const int dout = blockIdx.x;
  const int t = threadIdx.x;
#pragma unroll
  for (int p = 0; p < 2; ++p) {
    int din = t + p * 256;
    Wt[dout * D_ + din] = (bf16)W[din * D_ + dout];
  }
}

// ---------------------------------------------------------------------------
// k_wa: wa1 = W @ a1, wa2 = W @ a2 (fp32-exact logits path)
// ---------------------------------------------------------------------------
__global__ __launch_bounds__(256) void k_wa(const float* __restrict__ W,
                                            const float* __restrict__ a1,
                                            const float* __restrict__ a2,
                                            float* __restrict__ wa1,
                                            float* __restrict__ wa2) {
  const int wv = threadIdx.x >> 6, lane = threadIdx.x & 63;
  const int row = blockIdx.x * 4 + wv;
  const float* wr = W + (size_t)row * D_;
  float d1 = 0.f, d2 = 0.f;
#pragma unroll
  for (int p = 0; p < 8; ++p) {
    int c = lane + p * 64;
    float w = wr[c];
    d1 = fmaf(w, a1[c], d1);
    d2 = fmaf(w, a2[c], d2);
  }
#pragma unroll
  for (int off = 32; off > 0; off >>= 1) {
    d1 += __shfl_down(d1, off, 64);
    d2 += __shfl_down(d2, off, 64);
  }
  if (lane == 0) {
    wa1[row] = d1;
    wa2[row] = d2;
  }
}

// ---------------------------------------------------------------------------
// k_scores_x: s1[r] = X[r,:].wa1 ; s2[r] = X[r,:].wa2 (fp32, coalesced)
// ---------------------------------------------------------------------------
__global__ __launch_bounds__(256) void k_scores_x(const float* __restrict__ X,
                                                  const float* __restrict__ wa1,
                                                  const float* __restrict__ wa2,
                                                  float* __restrict__ s1,
                                                  float* __restrict__ s2) {
  const int wv = threadIdx.x >> 6, lane = threadIdx.x & 63;
  const int r = blockIdx.x * 4 + wv;
  const float* x = X + (size_t)r * D_;
  float d1 = 0.f, d2 = 0.f;
#pragma unroll
  for (int p = 0; p < 2; ++p) {
    int c = lane * 4 + p * 256;
    float4 xv = *(const float4*)&x[c];
    float4 w1 = *(const float4*)&wa1[c];
    float4 w2 = *(const float4*)&wa2[c];
    d1 += xv.x * w1.x + xv.y * w1.y + xv.z * w1.z + xv.w * w1.w;
    d2 += xv.x * w2.x + xv.y * w2.y + xv.z * w2.z + xv.w * w2.w;
  }
#pragma unroll
  for (int off = 32; off > 0; off >>= 1) {
    d1 += __shfl_down(d1, off, 64);
    d2 += __shfl_down(d2, off, 64);
  }
  if (lane == 0) {
    s1[r] = d1;
    s2[r] = d2;
  }
}

// ---------------------------------------------------------------------------
// k_hiddenT: Ht[dout][row] = bf16(sum_din Wt[dout][din] * X[row][din])
// BM=BN=128, BK=32, 256 thr, 16x16x32 MFMA + depth-1 register prefetch.
// ---------------------------------------------------------------------------
#define LDH 40

__global__ __launch_bounds__(256, 2) void k_hiddenT(const float* __restrict__ X,
                                                    const bf16* __restrict__ Wt,
                                                    bf16* __restrict__ Ht) {
  __shared__ bf16 As[128][LDH];
  __shared__ bf16 Bs[128][LDH];
  const int t = threadIdx.x;
  const int m0 = blockIdx.y * 128;
  const int n0 = blockIdx.x * 128;
  const int lane = t & 63, w = t >> 6;
  const int wm = w >> 1, wn = w & 1;
  const int l15 = lane & 15, q = lane >> 4;

  f32x4 acc[4][4];
#pragma unroll
  for (int i = 0; i < 4; ++i)
#pragma unroll
    for (int j = 0; j < 4; ++j) acc[i][j] = (f32x4){0.f, 0.f, 0.f, 0.f};

  bf16x8 av[2];
  float4 bv[4];
  // prologue loads (k0 = 0)
#pragma unroll
  for (int p = 0; p < 2; ++p) {
    int s = t + p * 256;
    av[p] = *(const bf16x8*)&Wt[(size_t)(m0 + (s >> 2)) * D_ + (s & 3) * 8];
  }
#pragma unroll
  for (int p = 0; p < 4; ++p) {
    int s = t + p * 256;
    bv[p] = *(const float4*)&X[(size_t)(n0 + (s >> 3)) * D_ + (s & 7) * 4];
  }

  for (int k0 = 0; k0 < D_; k0 += 32) {
    __syncthreads();  // previous iteration's readers done
#pragma unroll
    for (int p = 0; p < 2; ++p) {
      int s = t + p * 256;
      *(bf16x8*)&As[s >> 2][(s & 3) * 8] = av[p];
    }
#pragma unroll
    for (int p = 0; p < 4; ++p) {
      int s = t + p * 256;
      float4 v = bv[p];
      bf16x4 h = {(bf16)v.x, (bf16)v.y, (bf16)v.z, (bf16)v.w};
      *(bf16x4*)&Bs[s >> 3][(s & 7) * 4] = h;
    }
    __syncthreads();
    // prefetch next chunk
    if (k0 + 32 < D_) {
#pragma unroll
      for (int p = 0; p < 2; ++p) {
        int s = t + p * 256;
        av[p] = *(const bf16x8*)&Wt[(size_t)(m0 + (s >> 2)) * D_ + k0 + 32 + (s & 3) * 8];
      }
#pragma unroll
      for (int p = 0; p < 4; ++p) {
        int s = t + p * 256;
        bv[p] = *(const float4*)&X[(size_t)(n0 + (s >> 3)) * D_ + k0 + 32 + (s & 7) * 4];
      }
    }
    bf16x8 a[4], bb[4];
#pragma unroll
    for (int i = 0; i < 4; ++i)
      a[i] = *(const bf16x8*)&As[wm * 64 + i * 16 + l15][q * 8];
#pragma unroll
    for (int j = 0; j < 4; ++j)
      bb[j] = *(const bf16x8*)&Bs[wn * 64 + j * 16 + l15][q * 8];
#pragma unroll
    for (int i = 0; i < 4; ++i)
#pragma unroll
      for (int j = 0; j < 4; ++j)
        acc[i][j] =
            __builtin_amdgcn_mfma_f32_16x16x32_bf16(a[i], bb[j], acc[i][j], 0, 0, 0);
  }
#pragma unroll
  for (int i = 0; i < 4; ++i)
#pragma unroll
    for (int r = 0; r < 4; ++r) {
      int dout = m0 + wm * 64 + i * 16 + q * 4 + r;
#pragma unroll
      for (int j = 0; j < 4; ++j) {
        int row = n0 + wn * 64 + j * 16 + l15;
        Ht[(size_t)dout * NROWS + row] = (bf16)acc[i][j][r];
      }
    }
}

// ---------------------------------------------------------------------------
// k_attn: out = elu( softmax_row(mask(leaky(s1_i+s2_j))) @ H )
// 64 rows x 512 d per block, K=2048 in BK=64 chunks. 512 thr / 8 waves.
// 32x32x16 MFMA, wave-tile 64x64 (2x2 tiles). Depth-1 register prefetch of
// graph (HBM) and Ht chunk (L2/L3). LDS stride 72 bf16 (144 B, <=2-way banks).
// ---------------------------------------------------------------------------
#define AT_BM 64
#define AT_BK 64
#define LDP 72

__global__ __launch_bounds__(512, 1) void k_attn(const bf16* __restrict__ Ht,
                                                 const int* __restrict__ graph,
                                                 const float* __restrict__ s1,
                                                 const float* __restrict__ s2,
                                                 float* __restrict__ out) {
  __shared__ bf16 Hs[D_][LDP];          // 73,728 B [d][j]
  __shared__ bf16 Ps[AT_BM][LDP];       // 9,216 B  [i][j]
  __shared__ float s2s[N_];             // 8 KB
  __shared__ float sum_part[AT_BM][8];  // 2 KB
  __shared__ float row_sum[AT_BM];

  const int t = threadIdx.x;
  const int b = blockIdx.y;
  const int i0 = blockIdx.x * AT_BM;
  const int lane = t & 63, w = t >> 6;
  const int r31 = lane & 31, half = lane >> 5;

  const bf16* Htb = Ht + (size_t)b * N_;
  const int* Gb = graph + ((size_t)b * N_ + i0) * N_;

  for (int c = t; c < N_; c += 512) s2s[c] = s2[b * N_ + c];

  const int pi = t >> 3;       // P row 0..63
  const int pj = (t & 7) * 8;  // P j-offset (8 values/thread)
  const float s1r = s1[b * N_ + i0 + pi];
  float rsum = 0.f;

  f32x16 acc[2][2];
#pragma unroll
  for (int i = 0; i < 2; ++i)
#pragma unroll
    for (int j = 0; j < 2; ++j)
#pragma unroll
      for (int r = 0; r < 16; ++r) acc[i][j][r] = 0.f;

  // prologue prefetch: iter 0
  bf16x8 hv[8];
  int4 g0, g1;
#pragma unroll
  for (int p = 0; p < 8; ++p) {
    int s = t + p * 512;
    hv[p] = *(const bf16x8*)&Htb[(size_t)(s >> 3) * NROWS + (s & 7) * 8];
  }
  g0 = *(const int4*)&Gb[(size_t)pi * N_ + pj];
  g1 = *(const int4*)&Gb[(size_t)pi * N_ + pj + 4];

  __syncthreads();  // s2s ready

  for (int j0 = 0; j0 < N_; j0 += AT_BK) {
    // compute P from prefetched graph regs
    float pv[8];
    {
      int gg[8] = {g0.x, g0.y, g0.z, g0.w, g1.x, g1.y, g1.z, g1.w};
#pragma unroll
      for (int q = 0; q < 8; ++q) {
        float e = s1r + s2s[j0 + pj + q];
        e = (e > 0.f) ? e : NEG_ALPHA * e;
        pv[q] = (gg[q] != 0) ? __expf(e) : 0.f;
        rsum += pv[q];
      }
    }
    __syncthreads();  // previous iteration's LDS readers done
#pragma unroll
    for (int p = 0; p < 8; ++p) {
      int s = t + p * 512;
      *(bf16x8*)&Hs[s >> 3][(s & 7) * 8] = hv[p];
    }
    {
      bf16x8 pb = {(bf16)pv[0], (bf16)pv[1], (bf16)pv[2], (bf16)pv[3],
                   (bf16)pv[4], (bf16)pv[5], (bf16)pv[6], (bf16)pv[7]};
      *(bf16x8*)&Ps[pi][pj] = pb;
    }
    __syncthreads();
    // prefetch next iteration (in flight across the MFMA phase)
    if (j0 + AT_BK < N_) {
#pragma unroll
      for (int p = 0; p < 8; ++p) {
        int s = t + p * 512;
        hv[p] = *(const bf16x8*)&Htb[(size_t)(s >> 3) * NROWS + j0 + AT_BK + (s & 7) * 8];
      }
      g0 = *(const int4*)&Gb[(size_t)pi * N_ + j0 + AT_BK + pj];
      g1 = *(const int4*)&Gb[(size_t)pi * N_ + j0 + AT_BK + pj + 4];
    }
    // MFMA phase: 4 k-steps of 16
#pragma unroll
    for (int ks = 0; ks < 4; ++ks) {
      const int ko = ks * 16 + half * 8;
      bf16x8 a0 = *(const bf16x8*)&Ps[r31][ko];
      bf16x8 a1 = *(const bf16x8*)&Ps[32 + r31][ko];
      bf16x8 b0 = *(const bf16x8*)&Hs[w * 64 + r31][ko];
      bf16x8 b1 = *(const bf16x8*)&Hs[w * 64 + 32 + r31][ko];
      acc[0][0] = __builtin_amdgcn_mfma_f32_32x32x16_bf16(a0, b0, acc[0][0], 0, 0, 0);
      acc[0][1] = __builtin_amdgcn_mfma_f32_32x32x16_bf16(a0, b1, acc[0][1], 0, 0, 0);
      acc[1][0] = __builtin_amdgcn_mfma_f32_32x32x16_bf16(a1, b0, acc[1][0], 0, 0, 0);
      acc[1][1] = __builtin_amdgcn_mfma_f32_32x32x16_bf16(a1, b1, acc[1][1], 0, 0, 0);
    }
  }

  // row sums
  sum_part[pi][t & 7] = rsum;
  __syncthreads();
  if (t < AT_BM) {
    float s = 0.f;
#pragma unroll
    for (int k = 0; k < 8; ++k) s += sum_part[t][k];
    row_sum[t] = s;
  }
  __syncthreads();

  // epilogue: normalize + elu + store
  // C/D layout (32x32): col = lane&31, row = (r&3) + 8*(r>>2) + 4*half
#pragma unroll
  for (int mt = 0; mt < 2; ++mt) {
    float inv[16];
#pragma unroll
    for (int r = 0; r < 16; ++r)
      inv[r] = 1.f / row_sum[mt * 32 + (r & 3) + 8 * (r >> 2) + 4 * half];
#pragma unroll
    for (int nt = 0; nt < 2; ++nt) {
      const int d = w * 64 + nt * 32 + r31;
#pragma unroll
      for (int r = 0; r < 16; ++r) {
        int i = mt * 32 + (r & 3) + 8 * (r >> 2) + 4 * half;
        float x = acc[mt][nt][r] * inv[r];
        out[((size_t)b * N_ + i0 + i) * D_ + d] = (x > 0.f) ? x : expm1f(x);
      }
    }
  }
}

// ---------------------------------------------------------------------------
extern "C" void kernel_launch(void* const* d_in, const int* in_sizes, int n_in,
                              void* d_out, int out_size, void* d_ws,
                              size_t ws_size, hipStream_t stream) {
  const float* X = (const float*)d_in[0];
  const int* graph = (const int*)d_in[1];
  const float* W = (const float*)d_in[2];
  const float* a1 = (const float*)d_in[3];
  const float* a2 = (const float*)d_in[4];
  float* out = (float*)d_out;

  char* ws = (char*)d_ws;
  bf16* Wt = (bf16*)ws;                               // 512 KB
  bf16* Ht = (bf16*)(ws + (1 << 19));                 // 16 MB
  float* s1 = (float*)(ws + (1 << 19) + (16 << 20));
  float* s2 = s1 + NROWS;
  float* wa1 = s2 + NROWS;
  float* wa2 = wa1 + D_;

  hipLaunchKernelGGL(k_prep, dim3(512), dim3(256), 0, stream, W, Wt);
  hipLaunchKernelGGL(k_wa, dim3(128), dim3(256), 0, stream, W, a1, a2, wa1, wa2);
  hipLaunchKernelGGL(k_scores_x, dim3(NROWS / 4), dim3(256), 0, stream, X, wa1,
                     wa2, s1, s2);
  hipLaunchKernelGGL(k_hiddenT, dim3(NROWS / 128, D_ / 128), dim3(256), 0,
                     stream, X, Wt, Ht);
  hipLaunchKernelGGL(k_attn, dim3(N_ / AT_BM, B_), dim3(512), 0, stream, Ht,
                     graph, s1, s2, out);
}